// Round 7
// baseline (233.553 us; speedup 1.0000x reference)
//
#include <hip/hip_runtime.h>

#define ALPHA     10.0f
#define INV_BETA  20.0f      // 1/0.05
#define FAR_DELTA 1e10f
#define NSAMP     128
#define CH        8           // samples per chunk
#define NCHUNK    (NSAMP/CH)  // 16
#define RPB       256         // rays per block (= threads per block)
#define SD_STRIDE 12          // dist/depth LDS row stride (floats): 8+4 pad, 48 B rows (16B aligned)
#define SC_STRIDE 28          // color LDS row stride: 24+4 pad, 112 B rows (16B aligned)

// R7: no cross-lane ops at all. One thread = one ray, sequential cumsum
// (exact reference order). Samples reach the thread via LDS transpose:
// coalesced global dwordx4 -> regs -> padded LDS rows -> per-thread row reads.
// R3-R6 all plateaued at ~2.6 TB/s logical read with shfl-scan structures;
// this is the A/B against the serial ds_bpermute dependency chain.
__global__ __launch_bounds__(256) void volsdf_render(
    const float* __restrict__ dist,    // [R,128]
    const float* __restrict__ color,   // [R,128,3]
    const float* __restrict__ depth,   // [R,128]
    float*       __restrict__ out,     // [R*3] ray colors (geometry pre-zeroed by memset)
    int R)
{
    __shared__ float sd[RPB * SD_STRIDE];   // dist rows
    __shared__ float sp[RPB * SD_STRIDE];   // depth rows
    __shared__ float sc[RPB * SC_STRIDE];   // color rows (24 floats used)

    const int t  = threadIdx.x;
    const int R0 = blockIdx.x * RPB;
    if (R0 >= R) return;                    // R = 65536 = 256*256, blocks exact

    const float4* gd = (const float4*)dist;   // ray row = 32 float4
    const float4* gp = (const float4*)depth;
    const float4* gc = (const float4*)color;  // ray row = 96 float4

    // Prefetch registers for one chunk: 2+2+6 dwordx4 = 160 B/thread.
    float4 pd0, pd1, pp0, pp1, pc0, pc1, pc2, pc3, pc4, pc5;

    const int ray0 = t >> 1;                // dist/depth mapping: q=t+256k
    const int pos0 = t & 1;                 // ray=q>>1, pos=q&1

    auto issue_loads = [&](int c) {
        // dist/depth tile: 256 rays x 8 samples = 512 f4, 2 per thread.
        size_t b0 = (size_t)(R0 + ray0) * 32 + c * 2 + pos0;
        size_t b1 = (size_t)(R0 + 128 + ray0) * 32 + c * 2 + pos0;
        pd0 = gd[b0];  pd1 = gd[b1];
        pp0 = gp[b0];  pp1 = gp[b1];
        // color tile: 256 rays x 24 floats = 1536 f4, 6 per thread.
        // q = t + 256k -> ray = q/6, pos = q%6 (compiler magic-div).
        #pragma unroll
        for (int k = 0; k < 6; ++k) {
            int q = t + 256 * k;
            int ray = q / 6, pos = q % 6;
            float4 v = gc[(size_t)(R0 + ray) * 96 + c * 6 + pos];
            if (k == 0) pc0 = v; else if (k == 1) pc1 = v; else if (k == 2) pc2 = v;
            else if (k == 3) pc3 = v; else if (k == 4) pc4 = v; else pc5 = v;
        }
    };

    auto write_lds = [&]() {
        // All addresses 16 B aligned by stride choice -> ds_write_b128.
        *(float4*)&sd[ray0 * SD_STRIDE + pos0 * 4]         = pd0;
        *(float4*)&sd[(128 + ray0) * SD_STRIDE + pos0 * 4] = pd1;
        *(float4*)&sp[ray0 * SD_STRIDE + pos0 * 4]         = pp0;
        *(float4*)&sp[(128 + ray0) * SD_STRIDE + pos0 * 4] = pp1;
        #pragma unroll
        for (int k = 0; k < 6; ++k) {
            int q = t + 256 * k;
            int ray = q / 6, pos = q % 6;
            float4 v = (k == 0) ? pc0 : (k == 1) ? pc1 : (k == 2) ? pc2
                     : (k == 3) ? pc3 : (k == 4) ? pc4 : pc5;
            *(float4*)&sc[ray * SC_STRIDE + pos * 4] = v;
        }
    };

    // Per-ray sequential state (exact reference order).
    float tr = 1.f, aR = 0.f, aG = 0.f, aB = 0.f;
    float carD = 0.f, carR = 0.f, carG = 0.f, carB = 0.f, carP = 0.f;

    auto proc = [&](float sdf, float cr, float cg, float cb, float delta) {
        float s = -sdf;
        float e = __expf(-fabsf(s) * INV_BETA);
        float dens = (s <= 0.f) ? (0.5f * ALPHA * e) : (ALPHA * (1.f - 0.5f * e));
        float dd = dens * delta;
        float ee = __expf(-dd);
        float w  = tr * (1.f - ee);          // = exp(-T) - exp(-(T+dd))
        aR += w * cr; aG += w * cg; aB += w * cb;
        tr *= ee;
    };

    issue_loads(0);
    for (int c = 0; c < NCHUNK; ++c) {
        if (c) __syncthreads();              // prior compute done before overwrite
        write_lds();                         // ds_write waits vmcnt for its regs
        __syncthreads();
        if (c + 1 < NCHUNK) issue_loads(c + 1);   // in flight during compute

        // Read my ray's chunk: 10 aligned ds_read_b128.
        float4 d0 = *(const float4*)&sd[t * SD_STRIDE];
        float4 d1 = *(const float4*)&sd[t * SD_STRIDE + 4];
        float4 p0 = *(const float4*)&sp[t * SD_STRIDE];
        float4 p1 = *(const float4*)&sp[t * SD_STRIDE + 4];
        float cb_[24];
        *(float4*)&cb_[0]  = *(const float4*)&sc[t * SC_STRIDE];
        *(float4*)&cb_[4]  = *(const float4*)&sc[t * SC_STRIDE + 4];
        *(float4*)&cb_[8]  = *(const float4*)&sc[t * SC_STRIDE + 8];
        *(float4*)&cb_[12] = *(const float4*)&sc[t * SC_STRIDE + 12];
        *(float4*)&cb_[16] = *(const float4*)&sc[t * SC_STRIDE + 16];
        *(float4*)&cb_[20] = *(const float4*)&sc[t * SC_STRIDE + 20];

        float ds_[8] = { d0.x, d0.y, d0.z, d0.w, d1.x, d1.y, d1.z, d1.w };
        float pp_[8] = { p0.x, p0.y, p0.z, p0.w, p1.x, p1.y, p1.z, p1.w };

        // Carried sample from previous chunk gets its delta from this chunk's
        // first depth; samples 0..6 use in-chunk deltas; sample 7 is carried.
        if (c) proc(carD, carR, carG, carB, pp_[0] - carP);
        #pragma unroll
        for (int s = 0; s < 7; ++s)
            proc(ds_[s], cb_[s*3], cb_[s*3+1], cb_[s*3+2], pp_[s+1] - pp_[s]);
        carD = ds_[7]; carR = cb_[21]; carG = cb_[22]; carB = cb_[23]; carP = pp_[7];
    }
    // Last sample of the ray: FAR_DELTA.
    proc(carD, carR, carG, carB, FAR_DELTA);

    const size_t ray = (size_t)(R0 + t);
    out[ray * 3 + 0] = aR;
    out[ray * 3 + 1] = aG;
    out[ray * 3 + 2] = aB;
}

extern "C" void kernel_launch(void* const* d_in, const int* in_sizes, int n_in,
                              void* d_out, int out_size, void* d_ws, size_t ws_size,
                              hipStream_t stream) {
    const float* dist  = (const float*)d_in[0];
    const float* color = (const float*)d_in[1];
    const float* depth = (const float*)d_in[2];
    float* out = (float*)d_out;

    const int R = in_sizes[0] / NSAMP;       // 65536
    const int blocks = (R + RPB - 1) / RPB;  // 256 blocks = 1 per CU

    // Geometry zeros (+ color region, overwritten): write-only fill stream.
    hipMemsetAsync(d_out, 0, (size_t)out_size * sizeof(float), stream);

    hipLaunchKernelGGL(volsdf_render, dim3(blocks), dim3(256), 0, stream,
                       dist, color, depth, out, R);
}

// Round 8
// 213.723 us; speedup vs baseline: 1.0928x; 1.0928x over previous
//
#include <hip/hip_runtime.h>

#define ALPHA     10.0f
#define INV_BETA  20.0f      // 1/0.05
#define FAR_DELTA 1e10f
#define NSAMP     128        // samples per ray (reference N)
#define TCUT      8.0f       // skip color where cum-density >= 8: T<3.4e-4 << 1.9e-2 thr

__device__ __forceinline__ float laplace_density(float sdf) {
    // s = -sdf; s<=0 -> a*0.5*exp(s/b); s>0 -> a*(1-0.5*exp(-s/b))
    float s = -sdf;
    float e = __expf(-fabsf(s) * INV_BETA);
    return (s <= 0.f) ? (0.5f * ALPHA * e) : (ALPHA * (1.f - 0.5f * e));
}

// R8: traffic cut. R3/R6/R7 proved the kernel is bytes-shaped (~2.6 TB/s
// logical read regardless of structure/occupancy/MLP), so the lever is
// reading FEWER bytes: color (96 of 160 MB) is weighted by exp(-cumsum d);
// load it only while transmittance is significant. Scan needs just
// dist+depth (64 MB). Per-lane exec-masked loads skip whole cache lines.
// Half-wave (32 lanes) per ray, 4 samples per lane.
__global__ __launch_bounds__(256) void volsdf_render(
    const float* __restrict__ dist,    // [R,128]
    const float* __restrict__ color,   // [R,128,3]
    const float* __restrict__ depth,   // [R,128]
    float*       __restrict__ out,     // [R*3] ray colors (geometry pre-zeroed)
    int R)
{
    const int lane   = threadIdx.x & 63;
    const int waveId = threadIdx.x >> 6;
    const int sub    = lane & 31;              // sublane within half-wave
    const int half   = lane >> 5;              // which ray of the pair
    const int rayPair = blockIdx.x * 4 + waveId;
    const int ray     = rayPair * 2 + half;
    if (ray >= R) return;                      // wave-uniform for R % 8 == 0

    const size_t rbase = (size_t)ray * NSAMP;

    // ---- dist/depth loads (needed for the scan): 2x dwordx4 per lane ----
    float4 di = ((const float4*)(dist  + rbase))[sub];   // 4 SDF samples
    float4 dp = ((const float4*)(depth + rbase))[sub];   // 4 depths

    // ---- deltas: delta[j] = depth[j+1]-depth[j]; last sample -> FAR_DELTA
    float nx  = __shfl_down(dp.x, 1, 32);      // next sublane's first depth
    float dl0 = dp.y - dp.x;
    float dl1 = dp.z - dp.y;
    float dl2 = dp.w - dp.z;
    float dl3 = (sub == 31) ? FAR_DELTA : (nx - dp.w);

    float d0 = laplace_density(di.x) * dl0;
    float d1 = laplace_density(di.y) * dl1;
    float d2 = laplace_density(di.z) * dl2;
    float d3 = laplace_density(di.w) * dl3;    // sub31: ~1e11, never in a used prefix

    // ---- width-32 exclusive scan of per-lane sums (5 steps).
    // Base via shfl_up(incl,1), NOT (incl-local): sub31's ~1e11 local would
    // catastrophically cancel the O(10) base (R1 bug).
    float local = (d0 + d1) + (d2 + d3);
    float incl  = local;
    #pragma unroll
    for (int off = 1; off < 32; off <<= 1) {
        float v = __shfl_up(incl, off, 32);
        if (sub >= off) incl += v;
    }
    float base = __shfl_up(incl, 1, 32);
    if (sub == 0) base = 0.f;

    // ---- early-exit color: only lanes still transmitting load color.
    // Skipped contribution <= exp(-TCUT) = 3.4e-4 per channel (colors in [0,1]).
    float ar = 0.f, ag = 0.f, ab = 0.f;
    if (base < TCUT) {
        const float* cp = color + rbase * 3 + (size_t)sub * 12;
        float4 c0 = ((const float4*)cp)[0];    // r0 g0 b0 r1
        float4 c1 = ((const float4*)cp)[1];    // g1 b1 r2 g2
        float4 c2 = ((const float4*)cp)[2];    // b2 r3 g3 b3

        float p1 = base + d0, p2 = p1 + d1, p3 = p2 + d2;
        float w0 = (1.f - __expf(-d0)) * __expf(-base);
        float w1 = (1.f - __expf(-d1)) * __expf(-p1);
        float w2 = (1.f - __expf(-d2)) * __expf(-p2);
        float w3 = (1.f - __expf(-d3)) * __expf(-p3);

        ar = (w0 * c0.x + w1 * c0.w) + (w2 * c1.z + w3 * c2.y);
        ag = (w0 * c0.y + w1 * c1.x) + (w2 * c1.w + w3 * c2.z);
        ab = (w0 * c0.z + w1 * c1.y) + (w2 * c2.x + w3 * c2.w);
    }

    // ---- width-32 reduction (5 steps); sublane 0 of each half holds the sum
    #pragma unroll
    for (int off = 16; off > 0; off >>= 1) {
        ar += __shfl_down(ar, off, 32);
        ag += __shfl_down(ag, off, 32);
        ab += __shfl_down(ab, off, 32);
    }
    if (sub == 0) {
        out[(size_t)ray * 3 + 0] = ar;
        out[(size_t)ray * 3 + 1] = ag;
        out[(size_t)ray * 3 + 2] = ab;
    }
}

extern "C" void kernel_launch(void* const* d_in, const int* in_sizes, int n_in,
                              void* d_out, int out_size, void* d_ws, size_t ws_size,
                              hipStream_t stream) {
    const float* dist  = (const float*)d_in[0];
    const float* color = (const float*)d_in[1];
    const float* depth = (const float*)d_in[2];
    float* out = (float*)d_out;

    const int R = in_sizes[0] / NSAMP;         // 65536
    const int blocks = (R + 7) / 8;            // 8 rays per 256-thread block

    // Geometry zeros (+ color region, overwritten by kernel): write-only
    // fill stream at memset speed — graph-capturable memset node.
    hipMemsetAsync(d_out, 0, (size_t)out_size * sizeof(float), stream);

    hipLaunchKernelGGL(volsdf_render, dim3(blocks), dim3(256), 0, stream,
                       dist, color, depth, out, R);
}

// Round 9
// 207.942 us; speedup vs baseline: 1.1232x; 1.0278x over previous
//
#include <hip/hip_runtime.h>

#define ALPHA     10.0f
#define INV_BETA  20.0f      // 1/0.05
#define FAR_DELTA 1e10f
#define NSAMP     128        // samples per ray (reference N)
#define TCUT      8.0f       // trans < e^-8 = 3.4e-4 << 1.94e-2 threshold

__device__ __forceinline__ float laplace_density(float sdf) {
    // s = -sdf; s<=0 -> a*0.5*exp(s/b); s>0 -> a*(1-0.5*exp(-s/b))
    float s = -sdf;
    float e = __expf(-fabsf(s) * INV_BETA);
    return (s <= 0.f) ? (0.5f * ALPHA * e) : (ALPHA * (1.f - 0.5f * e));
}

// R9: bytes are the only lever left (R3-R8: ~2.6 TB/s logical regardless of
// structure). Ray split at sample 64: front dist/depth always read (32 MB);
// tail dist/depth + tail color read only while the ray still transmits at
// sample 63 (~3-5% of rays). Front color per-lane predicated as in R8.
// Half-wave (32 lanes) per ray, 2 front (+2 tail) samples per lane.
__global__ __launch_bounds__(256) void volsdf_render(
    const float* __restrict__ dist,    // [R,128]
    const float* __restrict__ color,   // [R,128,3]
    const float* __restrict__ depth,   // [R,128]
    float*       __restrict__ out,     // [R*3] ray colors (geometry pre-zeroed)
    int R)
{
    const int lane   = threadIdx.x & 63;
    const int waveId = threadIdx.x >> 6;
    const int sub    = lane & 31;              // sublane within half-wave
    const int half   = lane >> 5;              // which ray of the pair
    const int rayPair = blockIdx.x * 4 + waveId;
    const int ray     = rayPair * 2 + half;
    if (ray >= R) return;                      // wave-uniform for R % 8 == 0

    const size_t rbase = (size_t)ray * NSAMP;

    // ---- front (samples 0..63): 2 samples/lane, 8 B coalesced loads ----
    float2 di = ((const float2*)(dist  + rbase))[sub];
    float2 dp = ((const float2*)(depth + rbase))[sub];

    float nx  = __shfl_down(dp.x, 1, 32);      // depth[2i+2]
    float da  = laplace_density(di.x) * (dp.y - dp.x);
    // sample 63's delta needs depth[64] (tail) — defer; use 0 so w=0 for now.
    float db  = (sub == 31) ? 0.f : laplace_density(di.y) * (nx - dp.y);

    // ---- width-32 exclusive scan of per-lane pair sums (5 steps).
    // Base via shfl_up(incl,1), NOT (incl-local) — R1 cancellation bug.
    float local = da + db;
    float incl  = local;
    #pragma unroll
    for (int off = 1; off < 32; off <<= 1) {
        float v = __shfl_up(incl, off, 32);
        if (sub >= off) incl += v;
    }
    float base = __shfl_up(incl, 1, 32);
    if (sub == 0) base = 0.f;
    float total_lo = __shfl(incl, 31, 32);     // sum d0..d62 (d63 deferred)

    float ar = 0.f, ag = 0.f, ab = 0.f;
    float2 c01, c23, c45;                      // front colors (scope for tail reuse)
    bool haveC = base < TCUT;
    if (haveC) {                               // per-lane exec-masked color load
        const float* cp = color + rbase * 3 + (size_t)sub * 6;
        c01 = ((const float2*)cp)[0];          // r0 g0
        c23 = ((const float2*)cp)[1];          // b0 r1
        c45 = ((const float2*)cp)[2];          // g1 b1
        float wa = (1.f - __expf(-da)) * __expf(-base);
        float wb = (1.f - __expf(-db)) * __expf(-(base + da));  // sub31: 0
        ar = wa * c01.x + wb * c23.y;
        ag = wa * c01.y + wb * c45.x;
        ab = wa * c23.x + wb * c45.y;
    }

    // ---- tail (samples 64..127): only while the ray still transmits ----
    if (total_lo < TCUT) {                     // uniform within the half-wave
        float2 dt = ((const float2*)(dist  + rbase + 64))[sub];
        float2 pt = ((const float2*)(depth + rbase + 64))[sub];

        // exact d63 now that depth[64] is known
        float depth64 = __shfl(pt.x, 0, 32);
        float d63l = laplace_density(di.y) * (depth64 - dp.y); // valid at sub31
        float d63  = __shfl(d63l, 31, 32);
        if (sub == 31 && haveC) {              // sample 63's color contribution
            float w63 = (1.f - __expf(-d63)) * __expf(-(base + da));
            ar += w63 * c23.y; ag += w63 * c45.x; ab += w63 * c45.y;
        }

        float nxt = __shfl_down(pt.x, 1, 32);
        float ea  = laplace_density(dt.x) * (pt.y - pt.x);
        float eb  = laplace_density(dt.y) *
                    ((sub == 31) ? FAR_DELTA : (nxt - pt.y)); // ~1e11, prefix-safe
        float loc2 = ea + eb;
        float inc2 = loc2;
        #pragma unroll
        for (int off = 1; off < 32; off <<= 1) {
            float v = __shfl_up(inc2, off, 32);
            if (sub >= off) inc2 += v;
        }
        float base2 = __shfl_up(inc2, 1, 32);
        if (sub == 0) base2 = 0.f;
        base2 += total_lo + d63;

        if (base2 < TCUT) {                    // per-lane tail color
            const float* cp = color + (rbase + 64) * 3 + (size_t)sub * 6;
            float2 t01 = ((const float2*)cp)[0];
            float2 t23 = ((const float2*)cp)[1];
            float2 t45 = ((const float2*)cp)[2];
            float wa = (1.f - __expf(-ea)) * __expf(-base2);
            float wb = (1.f - __expf(-eb)) * __expf(-(base2 + ea));
            ar += wa * t01.x + wb * t23.y;
            ag += wa * t01.y + wb * t45.x;
            ab += wa * t23.x + wb * t45.y;
        }
    }

    // ---- width-32 reduction (5 steps); sublane 0 of each half holds the sum
    #pragma unroll
    for (int off = 16; off > 0; off >>= 1) {
        ar += __shfl_down(ar, off, 32);
        ag += __shfl_down(ag, off, 32);
        ab += __shfl_down(ab, off, 32);
    }
    if (sub == 0) {
        out[(size_t)ray * 3 + 0] = ar;
        out[(size_t)ray * 3 + 1] = ag;
        out[(size_t)ray * 3 + 2] = ab;
    }
}

extern "C" void kernel_launch(void* const* d_in, const int* in_sizes, int n_in,
                              void* d_out, int out_size, void* d_ws, size_t ws_size,
                              hipStream_t stream) {
    const float* dist  = (const float*)d_in[0];
    const float* color = (const float*)d_in[1];
    const float* depth = (const float*)d_in[2];
    float* out = (float*)d_out;

    const int R = in_sizes[0] / NSAMP;         // 65536
    const int blocks = (R + 7) / 8;            // 8 rays per 256-thread block

    // Geometry zeros (+ color region, overwritten by kernel): write-only
    // fill stream at memset speed — graph-capturable memset node.
    hipMemsetAsync(d_out, 0, (size_t)out_size * sizeof(float), stream);

    hipLaunchKernelGGL(volsdf_render, dim3(blocks), dim3(256), 0, stream,
                       dist, color, depth, out, R);
}